// Round 1
// baseline (6171.557 us; speedup 1.0000x reference)
//
#include <hip/hip_runtime.h>
#include <math.h>

#define NLAY 8
#define BB 4
#define LL 512
#define DDIM 512
#define HH 16
#define KHD 32
#define FFD 2048
#define MMD 512
#define NDB 14
#define SCALEF 0.17677669529663687f

__device__ __forceinline__ float wredSum(float v) {
#pragma unroll
  for (int o = 32; o > 0; o >>= 1) v += __shfl_down(v, o);
  return v;
}
__device__ __forceinline__ float wredMax(float v) {
#pragma unroll
  for (int o = 32; o > 0; o >>= 1) v = fmaxf(v, __shfl_down(v, o));
  return v;
}

// ---------------- bucketize: searchsorted(BINS, d, 'left'), BINS=10..140 ----------------
__global__ void bucketize_kernel(const float* __restrict__ dist, int* __restrict__ didx, int n) {
  int i = blockIdx.x * 256 + threadIdx.x;
  if (i >= n) return;
  float d = dist[i];
  int c = 0;
#pragma unroll
  for (int t = 1; t <= NDB; ++t) c += (10.0f * (float)t < d) ? 1 : 0;
  didx[i] = c > (NDB - 1) ? (NDB - 1) : c;
}

// ---------------- h = cell_emb[cell_types] ----------------
__global__ void embed_kernel(const int* __restrict__ ct, const float* __restrict__ emb,
                             float* __restrict__ h, int n) {
  int i = blockIdx.x * 256 + threadIdx.x;
  if (i >= n) return;
  int bl = i >> 9, d = i & 511;
  h[i] = emb[ct[bl] * DDIM + d];
}

// ---------------- Vsum = Vqk+Vqr+Vkr [14,32]; EkrS[d] = sum_k Kkr[d,k] ----------------
__global__ void prep_kernel(const float* __restrict__ Vqk, const float* __restrict__ Vqr,
                            const float* __restrict__ Vkr, const float* __restrict__ Kkr,
                            float* __restrict__ Vsum, float* __restrict__ EkrS) {
  int tid = threadIdx.x;
  if (tid < NDB * KHD) Vsum[tid] = Vqk[tid] + Vqr[tid] + Vkr[tid];
  if (tid < NDB) {
    float s = 0.f;
    for (int kk = 0; kk < KHD; ++kk) s += Kkr[tid * KHD + kk];
    EkrS[tid] = s;
  }
}

// ---------------- qE/kE: out[b,l,h,d] = sum_k x[b,l,h*32+k] * Kr[d,k] ----------------
__global__ void proj_rel_kernel(const float* __restrict__ x, const float* __restrict__ Kr,
                                float* __restrict__ outp, int n) {
  int idx = blockIdx.x * 256 + threadIdx.x;
  if (idx >= n) return;
  int d = idx % NDB;
  int rest = idx / NDB;
  int h = rest & (HH - 1);
  int bl = rest >> 4;
  const float* xr = x + (size_t)bl * DDIM + h * KHD;
  const float* kr = Kr + d * KHD;
  float s = 0.f;
#pragma unroll
  for (int kk = 0; kk < KHD; ++kk) s += xr[kk] * kr[kk];
  outp[idx] = s;
}

// ---------------- generic tiled SGEMM: C = A[M,K] @ W[K,N] + bias, opt gelu ----------------
__global__ __launch_bounds__(256) void gemm_bias_act(
    const float* __restrict__ A, const float* __restrict__ W,
    const float* __restrict__ bias, float* __restrict__ C,
    int M, int N, int K, int act) {
  __shared__ float As[16][68];
  __shared__ float Ws[16][68];
  const int tid = threadIdx.x;
  const int row0 = blockIdx.y * 64, col0 = blockIdx.x * 64;
  const int ty = tid >> 4, tx = tid & 15;
  const int ar = tid >> 2, ac = (tid & 3) << 2;
  const int wr = tid >> 4, wc = (tid & 15) << 2;
  float acc[4][4] = {{0.f}};
  for (int k0 = 0; k0 < K; k0 += 16) {
    float4 av = *(const float4*)(A + (size_t)(row0 + ar) * K + k0 + ac);
    float4 wv = *(const float4*)(W + (size_t)(k0 + wr) * N + col0 + wc);
    As[ac + 0][ar] = av.x; As[ac + 1][ar] = av.y;
    As[ac + 2][ar] = av.z; As[ac + 3][ar] = av.w;
    Ws[wr][wc + 0] = wv.x; Ws[wr][wc + 1] = wv.y;
    Ws[wr][wc + 2] = wv.z; Ws[wr][wc + 3] = wv.w;
    __syncthreads();
#pragma unroll
    for (int kk = 0; kk < 16; ++kk) {
      float aa[4], ww[4];
#pragma unroll
      for (int i = 0; i < 4; ++i) aa[i] = As[kk][ty * 4 + i];
#pragma unroll
      for (int j = 0; j < 4; ++j) ww[j] = Ws[kk][tx * 4 + j];
#pragma unroll
      for (int i = 0; i < 4; ++i)
#pragma unroll
        for (int j = 0; j < 4; ++j) acc[i][j] += aa[i] * ww[j];
    }
    __syncthreads();
  }
#pragma unroll
  for (int i = 0; i < 4; ++i) {
    int r = row0 + ty * 4 + i;
#pragma unroll
    for (int j = 0; j < 4; ++j) {
      int c = col0 + tx * 4 + j;
      float vv = acc[i][j] + bias[c];
      if (act == 1) vv = 0.5f * vv * (1.0f + erff(vv * 0.70710678118654752f));
      C[(size_t)r * N + c] = vv;
    }
  }
}

// ---------------- fused attention: one block per (l,h,b) row ----------------
__global__ __launch_bounds__(256) void attn_kernel(
    const float* __restrict__ q, const float* __restrict__ k, const float* __restrict__ v,
    const float* __restrict__ qE, const float* __restrict__ kE,
    const int* __restrict__ didx, const float* __restrict__ Vsum,
    const float* __restrict__ EkrS, float* __restrict__ z) {
  const int l = blockIdx.x, h = blockIdx.y, b = blockIdx.z;
  const int tid = threadIdx.x;
  const int lane = tid & 63, wid = tid >> 6;
  __shared__ float sc[LL];
  __shared__ float qrow[KHD];
  __shared__ float qEl[NDB];
  __shared__ float aB[NDB];
  __shared__ float red[4];
  __shared__ float zpart[8][KHD];

  const size_t blq = (size_t)(b * LL + l);
  if (tid < KHD) qrow[tid] = q[blq * DDIM + h * KHD + tid];
  if (tid < NDB) { qEl[tid] = qE[(blq * HH + h) * NDB + tid]; aB[tid] = 0.f; }
  __syncthreads();

  const int* drow = didx + blq * LL;
  float sloc[2];
  int dloc[2];
#pragma unroll
  for (int it = 0; it < 2; ++it) {
    const int x = tid + it * 256;
    const float4* krow = (const float4*)(k + ((size_t)(b * LL + x) * DDIM + h * KHD));
    float s = 0.f;
#pragma unroll
    for (int kk = 0; kk < 8; ++kk) {
      float4 kv = krow[kk];
      s += qrow[kk * 4 + 0] * kv.x + qrow[kk * 4 + 1] * kv.y +
           qrow[kk * 4 + 2] * kv.z + qrow[kk * 4 + 3] * kv.w;
    }
    const int dd = drow[x];
    dloc[it] = dd;
    s += qEl[dd] + kE[((size_t)(b * LL + x) * HH + h) * NDB + dd] + EkrS[dd];
    sloc[it] = s * SCALEF;
  }
  // block max
  float m = fmaxf(sloc[0], sloc[1]);
  m = wredMax(m);
  if (lane == 0) red[wid] = m;
  __syncthreads();
  m = fmaxf(fmaxf(red[0], red[1]), fmaxf(red[2], red[3]));
  __syncthreads();
  float e0 = expf(sloc[0] - m), e1 = expf(sloc[1] - m);
  sc[tid] = e0; sc[tid + 256] = e1;
  atomicAdd(&aB[dloc[0]], e0);
  atomicAdd(&aB[dloc[1]], e1);
  float ssum = wredSum(e0 + e1);
  if (lane == 0) red[wid] = ssum;
  __syncthreads();
  const float S = red[0] + red[1] + red[2] + red[3];
  const float inv = 1.f / S;

  // z = (sum_x e[x]*v[x,:] + sum_d aB[d]*Vsum[d,:]) * inv
  const int kk2 = tid & 31, ch = tid >> 5;
  const float* vbase = v + ((size_t)b * LL) * DDIM + h * KHD + kk2;
  float acc = 0.f;
#pragma unroll 8
  for (int i = 0; i < 64; ++i) {
    int x = ch * 64 + i;
    acc += sc[x] * vbase[(size_t)x * DDIM];
  }
  zpart[ch][kk2] = acc;
  __syncthreads();
  if (tid < KHD) {
    float zz = 0.f;
#pragma unroll
    for (int c = 0; c < 8; ++c) zz += zpart[c][tid];
    float bb = 0.f;
#pragma unroll
    for (int d = 0; d < NDB; ++d) bb += aB[d] * Vsum[d * KHD + tid];
    z[blq * DDIM + h * KHD + tid] = (zz + bb) * inv;
  }
}

// ---------------- out = LN(X + Y) ----------------
__global__ __launch_bounds__(256) void add_ln_kernel(
    const float* __restrict__ X, const float* __restrict__ Y,
    const float* __restrict__ g, const float* __restrict__ be,
    float* __restrict__ out) {
  const int row = blockIdx.x, tid = threadIdx.x;
  const int lane = tid & 63, wid = tid >> 6;
  __shared__ float red[4];
  const size_t base = (size_t)row * DDIM;
  float x0 = X[base + tid] + Y[base + tid];
  float x1 = X[base + tid + 256] + Y[base + tid + 256];
  float s = wredSum(x0 + x1);
  if (lane == 0) red[wid] = s;
  __syncthreads();
  float mu = (red[0] + red[1] + red[2] + red[3]) * (1.0f / DDIM);
  __syncthreads();
  float d0 = x0 - mu, d1 = x1 - mu;
  float vs = wredSum(d0 * d0 + d1 * d1);
  if (lane == 0) red[wid] = vs;
  __syncthreads();
  float var = (red[0] + red[1] + red[2] + red[3]) * (1.0f / DDIM);
  float inv = rsqrtf(var + 1e-5f);
  out[base + tid] = d0 * inv * g[tid] + be[tid];
  out[base + tid + 256] = d1 * inv * g[tid + 256] + be[tid + 256];
}

// ---------------- pooled[b,d] = sum_l h[b,l,d] ----------------
__global__ void pool_kernel(const float* __restrict__ h, float* __restrict__ pooled, int n) {
  int i = blockIdx.x * 256 + threadIdx.x;
  if (i >= n) return;
  int b = i >> 9, d = i & 511;
  float s = 0.f;
  for (int l = 0; l < LL; ++l) s += h[(size_t)(b * LL + l) * DDIM + d];
  pooled[i] = s;
}

// ---------------- out[b] = relu(pooled@Wm1+bm1)@Wm2 + bm2 ----------------
__global__ __launch_bounds__(256) void head_kernel(
    const float* __restrict__ pooled, const float* __restrict__ Wm1,
    const float* __restrict__ bm1, const float* __restrict__ Wm2,
    const float* __restrict__ bm2, float* __restrict__ out) {
  int b = blockIdx.x, tid = threadIdx.x;
  const float* p = pooled + b * DDIM;
  float part = 0.f;
  for (int jj = 0; jj < 2; ++jj) {
    int j = tid + jj * 256;
    float s = bm1[j];
    for (int dd = 0; dd < DDIM; ++dd) s += p[dd] * Wm1[(size_t)dd * MMD + j];
    part += fmaxf(s, 0.f) * Wm2[j];
  }
  __shared__ float red[4];
  int lane = tid & 63, wid = tid >> 6;
  float ssum = wredSum(part);
  if (lane == 0) red[wid] = ssum;
  __syncthreads();
  if (tid == 0) out[b] = red[0] + red[1] + red[2] + red[3] + bm2[0];
}

extern "C" void kernel_launch(void* const* d_in, const int* in_sizes, int n_in,
                              void* d_out, int out_size, void* d_ws, size_t ws_size,
                              hipStream_t stream) {
  const int* cell_types = (const int*)d_in[0];
  const float* distances = (const float*)d_in[1];
  const float* cell_emb = (const float*)d_in[2];
  const float* Kqk = (const float*)d_in[3];
  const float* Kqr = (const float*)d_in[4];
  const float* Kkr = (const float*)d_in[5];
  const float* Vqk = (const float*)d_in[6];
  const float* Vqr = (const float*)d_in[7];
  const float* Vkr = (const float*)d_in[8];
  const float* Wq = (const float*)d_in[9];
  const float* Wk = (const float*)d_in[10];
  const float* Wv = (const float*)d_in[11];
  const float* Wo = (const float*)d_in[12];
  const float* bq = (const float*)d_in[13];
  const float* bk = (const float*)d_in[14];
  const float* bv = (const float*)d_in[15];
  const float* bo = (const float*)d_in[16];
  const float* W1 = (const float*)d_in[17];
  const float* b1 = (const float*)d_in[18];
  const float* W2 = (const float*)d_in[19];
  const float* b2 = (const float*)d_in[20];
  const float* g1 = (const float*)d_in[21];
  const float* be1 = (const float*)d_in[22];
  const float* g2 = (const float*)d_in[23];
  const float* be2 = (const float*)d_in[24];
  const float* Wm1 = (const float*)d_in[25];
  const float* bm1 = (const float*)d_in[26];
  const float* Wm2 = (const float*)d_in[27];
  const float* bm2 = (const float*)d_in[28];

  char* w = (char*)d_ws;
  auto alloc = [&](size_t bytes) { void* p = (void*)w; w += (bytes + 255) & ~(size_t)255; return p; };
  int* didx   = (int*)alloc(sizeof(int) * BB * LL * LL);
  float* h    = (float*)alloc(sizeof(float) * BB * LL * DDIM);
  float* h2   = (float*)alloc(sizeof(float) * BB * LL * DDIM);
  float* qb   = (float*)alloc(sizeof(float) * BB * LL * DDIM);
  float* kb   = (float*)alloc(sizeof(float) * BB * LL * DDIM);
  float* vb   = (float*)alloc(sizeof(float) * BB * LL * DDIM);
  float* zb   = (float*)alloc(sizeof(float) * BB * LL * DDIM);
  float* f1   = (float*)alloc(sizeof(float) * BB * LL * FFD);
  float* qE   = (float*)alloc(sizeof(float) * BB * LL * HH * NDB);
  float* kEb  = (float*)alloc(sizeof(float) * BB * LL * HH * NDB);
  float* Vsum = (float*)alloc(sizeof(float) * NDB * KHD);
  float* EkrS = (float*)alloc(sizeof(float) * NDB);
  float* pooled = (float*)alloc(sizeof(float) * BB * DDIM);

  const int Mrows = BB * LL;

  bucketize_kernel<<<(BB * LL * LL + 255) / 256, 256, 0, stream>>>(distances, didx, BB * LL * LL);
  embed_kernel<<<(BB * LL * DDIM + 255) / 256, 256, 0, stream>>>(cell_types, cell_emb, h, BB * LL * DDIM);
  prep_kernel<<<1, 512, 0, stream>>>(Vqk, Vqr, Vkr, Kkr, Vsum, EkrS);

  dim3 g512(DDIM / 64, Mrows / 64);
  dim3 gff(FFD / 64, Mrows / 64);
  const int nrel = BB * LL * HH * NDB;

  for (int lay = 0; lay < NLAY; ++lay) {
    const float* wq = Wq + (size_t)lay * DDIM * DDIM;
    const float* wk = Wk + (size_t)lay * DDIM * DDIM;
    const float* wv = Wv + (size_t)lay * DDIM * DDIM;
    const float* wo = Wo + (size_t)lay * DDIM * DDIM;
    const float* bql = bq + (size_t)lay * DDIM;
    const float* bkl = bk + (size_t)lay * DDIM;
    const float* bvl = bv + (size_t)lay * DDIM;
    const float* bol = bo + (size_t)lay * DDIM;

    gemm_bias_act<<<g512, 256, 0, stream>>>(h, wq, bql, qb, Mrows, DDIM, DDIM, 0);
    gemm_bias_act<<<g512, 256, 0, stream>>>(h, wk, bkl, kb, Mrows, DDIM, DDIM, 0);
    gemm_bias_act<<<g512, 256, 0, stream>>>(h, wv, bvl, vb, Mrows, DDIM, DDIM, 0);
    proj_rel_kernel<<<(nrel + 255) / 256, 256, 0, stream>>>(qb, Kqk, qE, nrel);
    proj_rel_kernel<<<(nrel + 255) / 256, 256, 0, stream>>>(kb, Kqr, kEb, nrel);
    attn_kernel<<<dim3(LL, HH, BB), 256, 0, stream>>>(qb, kb, vb, qE, kEb, didx, Vsum, EkrS, zb);
    gemm_bias_act<<<g512, 256, 0, stream>>>(zb, wo, bol, qb /* o overwrites q */, Mrows, DDIM, DDIM, 0);
    add_ln_kernel<<<Mrows, 256, 0, stream>>>(h, qb, g1 + (size_t)lay * DDIM, be1 + (size_t)lay * DDIM, h2);
    gemm_bias_act<<<gff, 256, 0, stream>>>(h2, W1 + (size_t)lay * DDIM * FFD, b1 + (size_t)lay * FFD,
                                           f1, Mrows, FFD, DDIM, 1);
    gemm_bias_act<<<g512, 256, 0, stream>>>(f1, W2 + (size_t)lay * FFD * DDIM, b2 + (size_t)lay * DDIM,
                                            zb /* f2 overwrites z */, Mrows, DDIM, FFD, 0);
    add_ln_kernel<<<Mrows, 256, 0, stream>>>(h2, zb, g2 + (size_t)lay * DDIM, be2 + (size_t)lay * DDIM, h);
  }

  pool_kernel<<<(BB * DDIM + 255) / 256, 256, 0, stream>>>(h, pooled, BB * DDIM);
  head_kernel<<<BB, 256, 0, stream>>>(pooled, Wm1, bm1, Wm2, bm2, (float*)d_out);
}

// Round 2
// 3612.631 us; speedup vs baseline: 1.7083x; 1.7083x over previous
//
#include <hip/hip_runtime.h>
#include <math.h>

#define NLAY 8
#define BB 4
#define LL 512
#define DDIM 512
#define HH 16
#define KHD 32
#define FFD 2048
#define MMD 512
#define NDB 14
#define SCALEF 0.17677669529663687f

typedef unsigned short u16;
typedef __attribute__((ext_vector_type(8))) short bf16x8;
typedef __attribute__((ext_vector_type(4))) float f32x4;

__device__ __forceinline__ u16 f2bf(float f) {
  unsigned u = __builtin_bit_cast(unsigned, f);
  u = (u + 0x7fffu + ((u >> 16) & 1u)) >> 16;
  return (u16)u;
}

__device__ __forceinline__ float wredSum(float v) {
#pragma unroll
  for (int o = 32; o > 0; o >>= 1) v += __shfl_down(v, o);
  return v;
}

// ---------------- bucketize: searchsorted(BINS, d, 'left'), BINS=10..140 -> uint8 ----------------
__global__ void bucketize_kernel(const float* __restrict__ dist, unsigned char* __restrict__ didx, int n) {
  int i = blockIdx.x * 256 + threadIdx.x;
  if (i >= n) return;
  float d = dist[i];
  int c = 0;
#pragma unroll
  for (int t = 1; t <= NDB; ++t) c += (10.0f * (float)t < d) ? 1 : 0;
  didx[i] = (unsigned char)(c > (NDB - 1) ? (NDB - 1) : c);
}

// ---------------- h = cell_emb[cell_types] ----------------
__global__ void embed_kernel(const int* __restrict__ ct, const float* __restrict__ emb,
                             float* __restrict__ h, int n) {
  int i = blockIdx.x * 256 + threadIdx.x;
  if (i >= n) return;
  int bl = i >> 9, d = i & 511;
  h[i] = emb[ct[bl] * DDIM + d];
}

// ---------------- Vsum = Vqk+Vqr+Vkr [14,32]; EkrS[d] = sum_k Kkr[d,k] ----------------
__global__ void prep_kernel(const float* __restrict__ Vqk, const float* __restrict__ Vqr,
                            const float* __restrict__ Vkr, const float* __restrict__ Kkr,
                            float* __restrict__ Vsum, float* __restrict__ EkrS) {
  int tid = threadIdx.x;
  if (tid < NDB * KHD) Vsum[tid] = Vqk[tid] + Vqr[tid] + Vkr[tid];
  if (tid < NDB) {
    float s = 0.f;
    for (int kk = 0; kk < KHD; ++kk) s += Kkr[tid * KHD + kk];
    EkrS[tid] = s;
  }
}

// ---------------- rel projection: out[((b*H+h)*L + l)*14 + d] = scale*(x[b,l,h,:]·Kr[d]) + scale*ekrs[d] ----------------
__global__ void proj_rel2_kernel(const float* __restrict__ x, const float* __restrict__ Kr,
                                 const float* __restrict__ ekrs, float* __restrict__ outp) {
  int idx = blockIdx.x * 256 + threadIdx.x;
  if (idx >= BB * HH * LL * NDB) return;
  int d = idx % NDB;
  int rest = idx / NDB;
  int l = rest & (LL - 1);
  int bh = rest >> 9;
  int h = bh & (HH - 1);
  int b = bh >> 4;
  const float* xr = x + ((size_t)(b * LL + l)) * DDIM + h * KHD;
  const float* kr = Kr + d * KHD;
  float s = 0.f;
#pragma unroll
  for (int kk = 0; kk < KHD; ++kk) s += xr[kk] * kr[kk];
  s *= SCALEF;
  if (ekrs) s += SCALEF * ekrs[d];
  outp[idx] = s;
}

// ---------------- convert q (scaled) and k to bf16, same [B*L,512] layout ----------------
__global__ void convert_qk_kernel(const float* __restrict__ q, const float* __restrict__ k,
                                  u16* __restrict__ qbf, u16* __restrict__ kbf) {
  int i = blockIdx.x * 256 + threadIdx.x;  // over n/4
  float4 a = ((const float4*)q)[i];
  ushort4 oa;
  oa.x = f2bf(a.x * SCALEF); oa.y = f2bf(a.y * SCALEF);
  oa.z = f2bf(a.z * SCALEF); oa.w = f2bf(a.w * SCALEF);
  ((ushort4*)qbf)[i] = oa;
  float4 c = ((const float4*)k)[i];
  ushort4 ob;
  ob.x = f2bf(c.x); ob.y = f2bf(c.y); ob.z = f2bf(c.z); ob.w = f2bf(c.w);
  ((ushort4*)kbf)[i] = ob;
}

// ---------------- v [b,x,h*32+kh] f32 -> vt [b,h,kh,x] bf16 ----------------
__global__ __launch_bounds__(256) void vtrans_kernel(const float* __restrict__ v, u16* __restrict__ vt) {
  const int h = blockIdx.x, b = blockIdx.y, tid = threadIdx.x;
  __shared__ u16 tile[KHD][520];
  for (int it = 0; it < 64; ++it) {
    int idx = it * 256 + tid;  // 16384
    int x = idx >> 5, kh = idx & 31;
    tile[kh][x] = f2bf(v[((size_t)(b * LL) + x) * DDIM + h * KHD + kh]);
  }
  __syncthreads();
  int r = tid >> 3, seg = tid & 7;
  uint4* dst = (uint4*)(vt + ((size_t)(b * HH + h) * KHD + r) * LL);
  const uint4* src = (const uint4*)(&tile[r][0]);
#pragma unroll
  for (int j = 0; j < 8; ++j) dst[seg + j * 8] = src[seg + j * 8];
}

// ---------------- flash attention with MFMA, relative biases, histogram Vbias ----------------
__global__ __launch_bounds__(256) void attn2_kernel(
    const u16* __restrict__ qbf, const u16* __restrict__ kbf,
    const u16* __restrict__ vtbf, const float* __restrict__ qE2,
    const float* __restrict__ kE2, const unsigned char* __restrict__ didx8,
    const float* __restrict__ Vsum, float* __restrict__ z) {
  const int qt = blockIdx.x, h = blockIdx.y, b = blockIdx.z;
  const int tid = threadIdx.x, lane = tid & 63, w = tid >> 6;
  const int lr = lane & 15, lg = lane >> 4;

  __shared__ u16 Vt[KHD][520];          // 33280 B
  __shared__ float kE2s[LL][NDB];       // 28672 B
  __shared__ float qEs[64][NDB];        // 3584 B
  __shared__ float hist[4][16][NDB];    // 3584 B
  __shared__ u16 Pt[4][16][40];         // 5120 B
  __shared__ float Vsums[NDB][KHD];     // 1792 B

  // --- stage V^T tile (bf16, padded rows) ---
  {
    const u16* vsrc = vtbf + ((size_t)(b * HH + h) * KHD) * LL;
    int r = tid >> 3, seg = tid & 7;
    const uint4* gs = (const uint4*)(vsrc + (size_t)r * LL);
    uint4* ls = (uint4*)(&Vt[r][0]);
#pragma unroll
    for (int j = 0; j < 8; ++j) ls[seg + j * 8] = gs[seg + j * 8];
  }
  // --- stage kE2 [512][14] ---
  {
    const float4* gs = (const float4*)(kE2 + (size_t)(b * HH + h) * LL * NDB);
    float4* ls = (float4*)(&kE2s[0][0]);
#pragma unroll
    for (int j = 0; j < 7; ++j) ls[tid + j * 256] = gs[tid + j * 256];
  }
  if (tid < 224) ((float4*)qEs)[tid] = ((const float4*)(qE2 + ((size_t)(b * HH + h) * LL + qt * 64) * NDB))[tid];
  if (tid < 112) ((float4*)Vsums)[tid] = ((const float4*)Vsum)[tid];
  if (tid < 224) { float4 zz = {0.f, 0.f, 0.f, 0.f}; ((float4*)hist)[tid] = zz; }

  const int row16 = qt * 64 + w * 16;  // global (within b) query row base of this wave
  const bf16x8 aQ = *(const bf16x8*)(qbf + ((size_t)(b * LL + row16 + lr)) * DDIM + h * KHD + lg * 8);

  __syncthreads();

  f32x4 o0 = {0.f, 0.f, 0.f, 0.f}, o1 = {0.f, 0.f, 0.f, 0.f};
  const f32x4 zero4 = {0.f, 0.f, 0.f, 0.f};
  float mrow[4] = {-1e30f, -1e30f, -1e30f, -1e30f};
  float rsum[4] = {0.f, 0.f, 0.f, 0.f};

  const unsigned char* dbase = didx8 + (size_t)b * LL * LL;
  const u16* kbase = kbf + (size_t)b * LL * DDIM + h * KHD + lg * 8;

  for (int ct = 0; ct < 16; ++ct) {
    const int x0 = ct * 32;
    bf16x8 bk0 = *(const bf16x8*)(kbase + (size_t)(x0 + lr) * DDIM);
    bf16x8 bk1 = *(const bf16x8*)(kbase + (size_t)(x0 + 16 + lr) * DDIM);
    f32x4 s0 = __builtin_amdgcn_mfma_f32_16x16x32_bf16(aQ, bk0, zero4, 0, 0, 0);
    f32x4 s1 = __builtin_amdgcn_mfma_f32_16x16x32_bf16(aQ, bk1, zero4, 0, 0, 0);

    float p0[4], p1[4], fac[4];
    int d0[4], d1[4];
#pragma unroll
    for (int i = 0; i < 4; ++i) {
      const int rl = lg * 4 + i;               // row within wave's 16
      const int l = row16 + rl;                // query row in [0,512)
      const unsigned char* dr = dbase + (size_t)l * LL + x0;
      d0[i] = dr[lr];
      d1[i] = dr[16 + lr];
      float v0 = s0[i] + qEs[w * 16 + rl][d0[i]] + kE2s[x0 + lr][d0[i]];
      float v1 = s1[i] + qEs[w * 16 + rl][d1[i]] + kE2s[x0 + 16 + lr][d1[i]];
      float cm = fmaxf(v0, v1);
      cm = fmaxf(cm, __shfl_xor(cm, 1));
      cm = fmaxf(cm, __shfl_xor(cm, 2));
      cm = fmaxf(cm, __shfl_xor(cm, 4));
      cm = fmaxf(cm, __shfl_xor(cm, 8));
      float nm = fmaxf(mrow[i], cm);
      fac[i] = __expf(mrow[i] - nm);
      mrow[i] = nm;
      p0[i] = __expf(v0 - nm);
      p1[i] = __expf(v1 - nm);
      rsum[i] = rsum[i] * fac[i] + p0[i] + p1[i];
      o0[i] *= fac[i];
      o1[i] *= fac[i];
    }
    __syncthreads();  // prior chunk's hist atomics drained
    if (lr < NDB) {
#pragma unroll
      for (int i = 0; i < 4; ++i) hist[w][lg * 4 + i][lr] *= fac[i];
    }
    __syncthreads();  // rescale visible before new adds
#pragma unroll
    for (int i = 0; i < 4; ++i) {
      atomicAdd(&hist[w][lg * 4 + i][d0[i]], p0[i]);
      atomicAdd(&hist[w][lg * 4 + i][d1[i]], p1[i]);
      Pt[w][lg * 4 + i][lr] = f2bf(p0[i]);
      Pt[w][lg * 4 + i][16 + lr] = f2bf(p1[i]);
    }
    __syncthreads();  // Pt visible
    bf16x8 aP = *(const bf16x8*)(&Pt[w][lr][lg * 8]);
    bf16x8 vb0 = *(const bf16x8*)(&Vt[lr][x0 + lg * 8]);
    bf16x8 vb1 = *(const bf16x8*)(&Vt[16 + lr][x0 + lg * 8]);
    o0 = __builtin_amdgcn_mfma_f32_16x16x32_bf16(aP, vb0, o0, 0, 0, 0);
    o1 = __builtin_amdgcn_mfma_f32_16x16x32_bf16(aP, vb1, o1, 0, 0, 0);
  }

  __syncthreads();  // final hist complete
#pragma unroll
  for (int i = 0; i < 4; ++i) {
    float s = rsum[i];
    s += __shfl_xor(s, 1);
    s += __shfl_xor(s, 2);
    s += __shfl_xor(s, 4);
    s += __shfl_xor(s, 8);
    const float inv = 1.0f / s;
    float b0 = 0.f, b1 = 0.f;
#pragma unroll
    for (int d = 0; d < NDB; ++d) {
      float a = hist[w][lg * 4 + i][d];
      b0 += a * Vsums[d][lr];
      b1 += a * Vsums[d][16 + lr];
    }
    const size_t orow = ((size_t)(b * LL + row16 + lg * 4 + i)) * DDIM + h * KHD;
    z[orow + lr] = (o0[i] + b0) * inv;
    z[orow + 16 + lr] = (o1[i] + b1) * inv;
  }
}

// ---------------- generic tiled SGEMM: C = A[M,K] @ W[K,N] + bias, opt gelu ----------------
__global__ __launch_bounds__(256) void gemm_bias_act(
    const float* __restrict__ A, const float* __restrict__ W,
    const float* __restrict__ bias, float* __restrict__ C,
    int M, int N, int K, int act) {
  __shared__ float As[16][68];
  __shared__ float Ws[16][68];
  const int tid = threadIdx.x;
  const int row0 = blockIdx.y * 64, col0 = blockIdx.x * 64;
  const int ty = tid >> 4, tx = tid & 15;
  const int ar = tid >> 2, ac = (tid & 3) << 2;
  const int wr = tid >> 4, wc = (tid & 15) << 2;
  float acc[4][4] = {{0.f}};
  for (int k0 = 0; k0 < K; k0 += 16) {
    float4 av = *(const float4*)(A + (size_t)(row0 + ar) * K + k0 + ac);
    float4 wv = *(const float4*)(W + (size_t)(k0 + wr) * N + col0 + wc);
    As[ac + 0][ar] = av.x; As[ac + 1][ar] = av.y;
    As[ac + 2][ar] = av.z; As[ac + 3][ar] = av.w;
    Ws[wr][wc + 0] = wv.x; Ws[wr][wc + 1] = wv.y;
    Ws[wr][wc + 2] = wv.z; Ws[wr][wc + 3] = wv.w;
    __syncthreads();
#pragma unroll
    for (int kk = 0; kk < 16; ++kk) {
      float aa[4], ww[4];
#pragma unroll
      for (int i = 0; i < 4; ++i) aa[i] = As[kk][ty * 4 + i];
#pragma unroll
      for (int j = 0; j < 4; ++j) ww[j] = Ws[kk][tx * 4 + j];
#pragma unroll
      for (int i = 0; i < 4; ++i)
#pragma unroll
        for (int j = 0; j < 4; ++j) acc[i][j] += aa[i] * ww[j];
    }
    __syncthreads();
  }
#pragma unroll
  for (int i = 0; i < 4; ++i) {
    int r = row0 + ty * 4 + i;
#pragma unroll
    for (int j = 0; j < 4; ++j) {
      int c = col0 + tx * 4 + j;
      float vv = acc[i][j] + bias[c];
      if (act == 1) vv = 0.5f * vv * (1.0f + erff(vv * 0.70710678118654752f));
      C[(size_t)r * N + c] = vv;
    }
  }
}

// ---------------- out = LN(X + Y) ----------------
__global__ __launch_bounds__(256) void add_ln_kernel(
    const float* __restrict__ X, const float* __restrict__ Y,
    const float* __restrict__ g, const float* __restrict__ be,
    float* __restrict__ out) {
  const int row = blockIdx.x, tid = threadIdx.x;
  const int lane = tid & 63, wid = tid >> 6;
  __shared__ float red[4];
  const size_t base = (size_t)row * DDIM;
  float x0 = X[base + tid] + Y[base + tid];
  float x1 = X[base + tid + 256] + Y[base + tid + 256];
  float s = wredSum(x0 + x1);
  if (lane == 0) red[wid] = s;
  __syncthreads();
  float mu = (red[0] + red[1] + red[2] + red[3]) * (1.0f / DDIM);
  __syncthreads();
  float d0 = x0 - mu, d1 = x1 - mu;
  float vs = wredSum(d0 * d0 + d1 * d1);
  if (lane == 0) red[wid] = vs;
  __syncthreads();
  float var = (red[0] + red[1] + red[2] + red[3]) * (1.0f / DDIM);
  float inv = rsqrtf(var + 1e-5f);
  out[base + tid] = d0 * inv * g[tid] + be[tid];
  out[base + tid + 256] = d1 * inv * g[tid + 256] + be[tid + 256];
}

// ---------------- pooled[b,d] = sum_l h[b,l,d] ----------------
__global__ void pool_kernel(const float* __restrict__ h, float* __restrict__ pooled, int n) {
  int i = blockIdx.x * 256 + threadIdx.x;
  if (i >= n) return;
  int b = i >> 9, d = i & 511;
  float s = 0.f;
  for (int l = 0; l < LL; ++l) s += h[(size_t)(b * LL + l) * DDIM + d];
  pooled[i] = s;
}

// ---------------- out[b] = relu(pooled@Wm1+bm1)@Wm2 + bm2 ----------------
__global__ __launch_bounds__(256) void head_kernel(
    const float* __restrict__ pooled, const float* __restrict__ Wm1,
    const float* __restrict__ bm1, const float* __restrict__ Wm2,
    const float* __restrict__ bm2, float* __restrict__ out) {
  int b = blockIdx.x, tid = threadIdx.x;
  const float* p = pooled + b * DDIM;
  float part = 0.f;
  for (int jj = 0; jj < 2; ++jj) {
    int j = tid + jj * 256;
    float s = bm1[j];
    for (int dd = 0; dd < DDIM; ++dd) s += p[dd] * Wm1[(size_t)dd * MMD + j];
    part += fmaxf(s, 0.f) * Wm2[j];
  }
  __shared__ float red[4];
  int lane = tid & 63, wid = tid >> 6;
  float ssum = wredSum(part);
  if (lane == 0) red[wid] = ssum;
  __syncthreads();
  if (tid == 0) out[b] = red[0] + red[1] + red[2] + red[3] + bm2[0];
}

extern "C" void kernel_launch(void* const* d_in, const int* in_sizes, int n_in,
                              void* d_out, int out_size, void* d_ws, size_t ws_size,
                              hipStream_t stream) {
  const int* cell_types = (const int*)d_in[0];
  const float* distances = (const float*)d_in[1];
  const float* cell_emb = (const float*)d_in[2];
  const float* Kqk = (const float*)d_in[3];
  const float* Kqr = (const float*)d_in[4];
  const float* Kkr = (const float*)d_in[5];
  const float* Vqk = (const float*)d_in[6];
  const float* Vqr = (const float*)d_in[7];
  const float* Vkr = (const float*)d_in[8];
  const float* Wq = (const float*)d_in[9];
  const float* Wk = (const float*)d_in[10];
  const float* Wv = (const float*)d_in[11];
  const float* Wo = (const float*)d_in[12];
  const float* bq = (const float*)d_in[13];
  const float* bk = (const float*)d_in[14];
  const float* bv = (const float*)d_in[15];
  const float* bo = (const float*)d_in[16];
  const float* W1 = (const float*)d_in[17];
  const float* b1 = (const float*)d_in[18];
  const float* W2 = (const float*)d_in[19];
  const float* b2 = (const float*)d_in[20];
  const float* g1 = (const float*)d_in[21];
  const float* be1 = (const float*)d_in[22];
  const float* g2 = (const float*)d_in[23];
  const float* be2 = (const float*)d_in[24];
  const float* Wm1 = (const float*)d_in[25];
  const float* bm1 = (const float*)d_in[26];
  const float* Wm2 = (const float*)d_in[27];
  const float* bm2 = (const float*)d_in[28];

  char* w = (char*)d_ws;
  auto alloc = [&](size_t bytes) { void* p = (void*)w; w += (bytes + 255) & ~(size_t)255; return p; };
  unsigned char* didx8 = (unsigned char*)alloc(sizeof(unsigned char) * BB * LL * LL);
  float* h    = (float*)alloc(sizeof(float) * BB * LL * DDIM);
  float* h2   = (float*)alloc(sizeof(float) * BB * LL * DDIM);
  float* qb   = (float*)alloc(sizeof(float) * BB * LL * DDIM);
  float* kb   = (float*)alloc(sizeof(float) * BB * LL * DDIM);
  float* vb   = (float*)alloc(sizeof(float) * BB * LL * DDIM);
  float* zb   = (float*)alloc(sizeof(float) * BB * LL * DDIM);
  float* f1   = (float*)alloc(sizeof(float) * BB * LL * FFD);
  float* qE2  = (float*)alloc(sizeof(float) * BB * HH * LL * NDB);
  float* kE2  = (float*)alloc(sizeof(float) * BB * HH * LL * NDB);
  u16* qbf    = (u16*)alloc(sizeof(u16) * BB * LL * DDIM);
  u16* kbf    = (u16*)alloc(sizeof(u16) * BB * LL * DDIM);
  u16* vtbf   = (u16*)alloc(sizeof(u16) * BB * HH * KHD * LL);
  float* Vsum = (float*)alloc(sizeof(float) * NDB * KHD);
  float* EkrS = (float*)alloc(sizeof(float) * NDB);
  float* pooled = (float*)alloc(sizeof(float) * BB * DDIM);

  const int Mrows = BB * LL;

  bucketize_kernel<<<(BB * LL * LL + 255) / 256, 256, 0, stream>>>(distances, didx8, BB * LL * LL);
  embed_kernel<<<(BB * LL * DDIM + 255) / 256, 256, 0, stream>>>(cell_types, cell_emb, h, BB * LL * DDIM);
  prep_kernel<<<1, 512, 0, stream>>>(Vqk, Vqr, Vkr, Kkr, Vsum, EkrS);

  dim3 g512(DDIM / 64, Mrows / 64);
  dim3 gff(FFD / 64, Mrows / 64);
  const int nrel = BB * HH * LL * NDB;
  const int ncv4 = BB * LL * DDIM / 4;

  for (int lay = 0; lay < NLAY; ++lay) {
    const float* wq = Wq + (size_t)lay * DDIM * DDIM;
    const float* wk = Wk + (size_t)lay * DDIM * DDIM;
    const float* wv = Wv + (size_t)lay * DDIM * DDIM;
    const float* wo = Wo + (size_t)lay * DDIM * DDIM;
    const float* bql = bq + (size_t)lay * DDIM;
    const float* bkl = bk + (size_t)lay * DDIM;
    const float* bvl = bv + (size_t)lay * DDIM;
    const float* bol = bo + (size_t)lay * DDIM;

    gemm_bias_act<<<g512, 256, 0, stream>>>(h, wq, bql, qb, Mrows, DDIM, DDIM, 0);
    gemm_bias_act<<<g512, 256, 0, stream>>>(h, wk, bkl, kb, Mrows, DDIM, DDIM, 0);
    gemm_bias_act<<<g512, 256, 0, stream>>>(h, wv, bvl, vb, Mrows, DDIM, DDIM, 0);
    convert_qk_kernel<<<ncv4 / 256, 256, 0, stream>>>(qb, kb, qbf, kbf);
    vtrans_kernel<<<dim3(HH, BB), 256, 0, stream>>>(vb, vtbf);
    proj_rel2_kernel<<<(nrel + 255) / 256, 256, 0, stream>>>(qb, Kqk, nullptr, qE2);
    proj_rel2_kernel<<<(nrel + 255) / 256, 256, 0, stream>>>(kb, Kqr, EkrS, kE2);
    attn2_kernel<<<dim3(8, HH, BB), 256, 0, stream>>>(qbf, kbf, vtbf, qE2, kE2, didx8, Vsum, zb);
    gemm_bias_act<<<g512, 256, 0, stream>>>(zb, wo, bol, qb /* o overwrites q */, Mrows, DDIM, DDIM, 0);
    add_ln_kernel<<<Mrows, 256, 0, stream>>>(h, qb, g1 + (size_t)lay * DDIM, be1 + (size_t)lay * DDIM, h2);
    gemm_bias_act<<<gff, 256, 0, stream>>>(h2, W1 + (size_t)lay * DDIM * FFD, b1 + (size_t)lay * FFD,
                                           f1, Mrows, FFD, DDIM, 1);
    gemm_bias_act<<<g512, 256, 0, stream>>>(f1, W2 + (size_t)lay * FFD * DDIM, b2 + (size_t)lay * DDIM,
                                            zb /* f2 overwrites z */, Mrows, DDIM, FFD, 0);
    add_ln_kernel<<<Mrows, 256, 0, stream>>>(h2, zb, g2 + (size_t)lay * DDIM, be2 + (size_t)lay * DDIM, h);
  }

  pool_kernel<<<(BB * DDIM + 255) / 256, 256, 0, stream>>>(h, pooled, BB * DDIM);
  head_kernel<<<BB, 256, 0, stream>>>(pooled, Wm1, bm1, Wm2, bm2, (float*)d_out);
}

// Round 3
// 1833.495 us; speedup vs baseline: 3.3660x; 1.9704x over previous
//
#include <hip/hip_runtime.h>
#include <math.h>

#define NLAY 8
#define BB 4
#define LL 512
#define DDIM 512
#define HH 16
#define KHD 32
#define FFD 2048
#define MMD 512
#define NDB 14
#define QKS 1536
#define SCALEF 0.17677669529663687f

typedef unsigned short u16;
typedef __attribute__((ext_vector_type(8))) short bf16x8;
typedef __attribute__((ext_vector_type(4))) float f32x4;

__device__ __forceinline__ u16 f2bf(float f) {
  unsigned u = __builtin_bit_cast(unsigned, f);
  u = (u + 0x7fffu + ((u >> 16) & 1u)) >> 16;
  return (u16)u;
}
__device__ __forceinline__ float bf2f(u16 v) {
  unsigned u = ((unsigned)v) << 16;
  return __builtin_bit_cast(float, u);
}
__device__ __forceinline__ float wredSum(float v) {
#pragma unroll
  for (int o = 32; o > 0; o >>= 1) v += __shfl_down(v, o);
  return v;
}
__device__ __forceinline__ void gload_lds16(const u16* g, u16* l) {
  __builtin_amdgcn_global_load_lds((const __attribute__((address_space(1))) void*)g,
                                   (__attribute__((address_space(3))) void*)l, 16, 0, 0);
}

// ---------------- bucketize -> uint8 ----------------
__global__ void bucketize_kernel(const float* __restrict__ dist, unsigned char* __restrict__ didx, int n) {
  int i = blockIdx.x * 256 + threadIdx.x;
  if (i >= n) return;
  float d = dist[i];
  int c = 0;
#pragma unroll
  for (int t = 1; t <= NDB; ++t) c += (10.0f * (float)t < d) ? 1 : 0;
  didx[i] = (unsigned char)(c > (NDB - 1) ? (NDB - 1) : c);
}

// ---------------- h = cell_emb[cell_types] (f32 + bf16) ----------------
__global__ void embed_kernel(const int* __restrict__ ct, const float* __restrict__ emb,
                             float* __restrict__ h, u16* __restrict__ hbf, int n) {
  int i = blockIdx.x * 256 + threadIdx.x;
  if (i >= n) return;
  int bl = i >> 9, d = i & 511;
  float v = emb[ct[bl] * DDIM + d];
  h[i] = v;
  hbf[i] = f2bf(v);
}

// ---------------- Vsum, EkrS ----------------
__global__ void prep_kernel(const float* __restrict__ Vqk, const float* __restrict__ Vqr,
                            const float* __restrict__ Vkr, const float* __restrict__ Kkr,
                            float* __restrict__ Vsum, float* __restrict__ EkrS) {
  int tid = threadIdx.x;
  if (tid < NDB * KHD) Vsum[tid] = Vqk[tid] + Vqr[tid] + Vkr[tid];
  if (tid < NDB) {
    float s = 0.f;
    for (int kk = 0; kk < KHD; ++kk) s += Kkr[tid * KHD + kk];
    EkrS[tid] = s;
  }
}

// ---------------- packed qkv bias [NLAY][1536] ----------------
__global__ void biaspack_kernel(const float* __restrict__ bq, const float* __restrict__ bk,
                                const float* __restrict__ bv, float* __restrict__ bqkv) {
  int i = blockIdx.x * 256 + threadIdx.x;
  if (i >= NLAY * QKS) return;
  int lay = i / QKS, c = i % QKS;
  float v;
  if (c < 512) v = bq[lay * DDIM + c];
  else if (c < 1024) v = bk[lay * DDIM + c - 512];
  else v = bv[lay * DDIM + c - 1024];
  bqkv[i] = v;
}

// ---------------- per-layer weight transpose+convert: src f32 [K,N] -> dst bf16 [N,K] ----------------
__device__ __forceinline__ void wtconv_tile(const float* __restrict__ src, u16* __restrict__ dst,
                                            int K, int N, int tn, int tk) {
  __shared__ float tl[64][65];
  const int t = threadIdx.x;
#pragma unroll
  for (int p = 0; p < 4; ++p) {
    int k = tk * 64 + p * 16 + (t >> 4);
    int n = tn * 64 + (t & 15) * 4;
    float4 v = *(const float4*)(src + (size_t)k * N + n);
    tl[(t & 15) * 4 + 0][p * 16 + (t >> 4)] = v.x;
    tl[(t & 15) * 4 + 1][p * 16 + (t >> 4)] = v.y;
    tl[(t & 15) * 4 + 2][p * 16 + (t >> 4)] = v.z;
    tl[(t & 15) * 4 + 3][p * 16 + (t >> 4)] = v.w;
  }
  __syncthreads();
  int n = t >> 2, cc = t & 3;
  u16 o[16];
#pragma unroll
  for (int e = 0; e < 16; ++e) o[e] = f2bf(tl[n][cc * 16 + e]);
  u16* dp = dst + (size_t)(tn * 64 + n) * K + tk * 64 + cc * 16;
  *(uint4*)(dp) = *(uint4*)&o[0];
  *(uint4*)(dp + 8) = *(uint4*)&o[8];
}

__global__ __launch_bounds__(256) void wconv_layer(
    const float* __restrict__ Wq, const float* __restrict__ Wk, const float* __restrict__ Wv,
    const float* __restrict__ Wo, const float* __restrict__ W1, const float* __restrict__ W2,
    u16* __restrict__ Wqkvt, u16* __restrict__ Wot, u16* __restrict__ W1t, u16* __restrict__ W2t) {
  int b = blockIdx.x;
  if (b < 64) { wtconv_tile(Wq, Wqkvt, 512, 512, b >> 3, b & 7); return; }
  if (b < 128) { b -= 64; wtconv_tile(Wk, Wqkvt + 512 * 512, 512, 512, b >> 3, b & 7); return; }
  if (b < 192) { b -= 128; wtconv_tile(Wv, Wqkvt + 1024 * 512, 512, 512, b >> 3, b & 7); return; }
  if (b < 256) { b -= 192; wtconv_tile(Wo, Wot, 512, 512, b >> 3, b & 7); return; }
  if (b < 512) { b -= 256; wtconv_tile(W1, W1t, 512, FFD, b >> 3, b & 7); return; }
  b -= 512; wtconv_tile(W2, W2t, FFD, 512, b >> 5, b & 31);
}

// ---------------- bf16 MFMA GEMM: C = A[M,K]bf16 @ Bt[N,K]bf16^T + bias ----------------
// 64x128 tile, BK=64, 4 waves (each 64x32), XOR-swizzled LDS, global_load_lds staging.
__global__ __launch_bounds__(256) void gemm_bf16(
    const u16* __restrict__ A, const u16* __restrict__ Bt, const float* __restrict__ bias,
    float* __restrict__ Cf, u16* __restrict__ Cb,
    int M, int N, int K, int act, int scaleLT) {
  __shared__ u16 As[64 * 64];
  __shared__ u16 Bs[128 * 64];
  const int tid = threadIdx.x, w = tid >> 6, lane = tid & 63;
  const int lr = lane & 15, lg = lane >> 4;
  const int row0 = blockIdx.y * 64, col0 = blockIdx.x * 128;
  const int srow = lane >> 3;                  // 0..7 within 8-row issue
  const int aoff = ((lane & 7) ^ srow) * 8;    // pre-swizzled global chunk
  const f32x4 z4 = {0.f, 0.f, 0.f, 0.f};
  f32x4 acc[4][2];
#pragma unroll
  for (int mi = 0; mi < 4; ++mi)
#pragma unroll
    for (int ni = 0; ni < 2; ++ni) acc[mi][ni] = z4;

  const int nw = w * 32;
  for (int k0 = 0; k0 < K; k0 += 64) {
#pragma unroll
    for (int i = 0; i < 2; ++i)
      gload_lds16(A + (size_t)(row0 + w * 16 + i * 8 + srow) * K + k0 + aoff,
                  As + (w * 16 + i * 8) * 64);
#pragma unroll
    for (int i = 0; i < 4; ++i)
      gload_lds16(Bt + (size_t)(col0 + w * 32 + i * 8 + srow) * K + k0 + aoff,
                  Bs + (w * 32 + i * 8) * 64);
    __syncthreads();
#pragma unroll
    for (int kh = 0; kh < 2; ++kh) {
      bf16x8 a[4], b[2];
#pragma unroll
      for (int mi = 0; mi < 4; ++mi) {
        int r = mi * 16 + lr;
        a[mi] = *(const bf16x8*)(As + r * 64 + (((kh * 4 + lg) ^ (r & 7)) << 3));
      }
#pragma unroll
      for (int ni = 0; ni < 2; ++ni) {
        int r = nw + ni * 16 + lr;
        b[ni] = *(const bf16x8*)(Bs + r * 64 + (((kh * 4 + lg) ^ (r & 7)) << 3));
      }
#pragma unroll
      for (int mi = 0; mi < 4; ++mi)
#pragma unroll
        for (int ni = 0; ni < 2; ++ni)
          acc[mi][ni] = __builtin_amdgcn_mfma_f32_16x16x32_bf16(a[mi], b[ni], acc[mi][ni], 0, 0, 0);
    }
    __syncthreads();
  }
  // epilogue: row = row0 + mi*16 + lg*4 + j, col = col0 + nw + ni*16 + lr
#pragma unroll
  for (int mi = 0; mi < 4; ++mi) {
    int r = row0 + mi * 16 + lg * 4;
#pragma unroll
    for (int ni = 0; ni < 2; ++ni) {
      int c = col0 + nw + ni * 16 + lr;
      float bs = bias[c];
      float sc = (c < scaleLT) ? SCALEF : 1.0f;
#pragma unroll
      for (int j = 0; j < 4; ++j) {
        float v = acc[mi][ni][j] + bs;
        if (act == 1) v = 0.5f * v * (1.0f + erff(v * 0.70710678118654752f));
        size_t idx = (size_t)(r + j) * N + c;
        if (Cf) Cf[idx] = v;
        if (Cb) Cb[idx] = f2bf(v * sc);
      }
    }
  }
}

// ---------------- rel projection from packed bf16 qkv ----------------
__global__ void proj_relbf_kernel(const u16* __restrict__ x, const float* __restrict__ Kr,
                                  const float* __restrict__ ekrs, float scale_mul,
                                  float* __restrict__ outp) {
  int idx = blockIdx.x * 256 + threadIdx.x;
  if (idx >= BB * HH * LL * NDB) return;
  int d = idx % NDB;
  int rest = idx / NDB;
  int l = rest & (LL - 1);
  int bh = rest >> 9;
  int h = bh & (HH - 1);
  int b = bh >> 4;
  const u16* xr = x + ((size_t)(b * LL + l)) * QKS + h * KHD;
  const float* kr = Kr + d * KHD;
  float s = 0.f;
#pragma unroll
  for (int kk = 0; kk < KHD; ++kk) s += bf2f(xr[kk]) * kr[kk];
  s *= scale_mul;
  if (ekrs) s += SCALEF * ekrs[d];
  outp[idx] = s;
}

// ---------------- v (packed bf16 cols 1024..1535) -> vt [b,h,kh,x] bf16 ----------------
__global__ __launch_bounds__(256) void vtrans_kernel(const u16* __restrict__ qkv, u16* __restrict__ vt) {
  const int h = blockIdx.x, b = blockIdx.y, tid = threadIdx.x;
  __shared__ u16 tile[KHD][520];
  for (int it = 0; it < 64; ++it) {
    int idx = it * 256 + tid;
    int x = idx >> 5, kh = idx & 31;
    tile[kh][x] = qkv[((size_t)(b * LL) + x) * QKS + 1024 + h * KHD + kh];
  }
  __syncthreads();
  int r = tid >> 3, seg = tid & 7;
  uint4* dst = (uint4*)(vt + ((size_t)(b * HH + h) * KHD + r) * LL);
  const uint4* src = (const uint4*)(&tile[r][0]);
#pragma unroll
  for (int j = 0; j < 8; ++j) dst[seg + j * 8] = src[seg + j * 8];
}

// ---------------- flash attention with MFMA (packed bf16 q/k), bf16 z out ----------------
__global__ __launch_bounds__(256) void attn2_kernel(
    const u16* __restrict__ qkv, const u16* __restrict__ vtbf, const float* __restrict__ qE2,
    const float* __restrict__ kE2, const unsigned char* __restrict__ didx8,
    const float* __restrict__ Vsum, u16* __restrict__ z) {
  const int qt = blockIdx.x, h = blockIdx.y, b = blockIdx.z;
  const int tid = threadIdx.x, lane = tid & 63, w = tid >> 6;
  const int lr = lane & 15, lg = lane >> 4;

  __shared__ u16 Vt[KHD][520];
  __shared__ float kE2s[LL][NDB];
  __shared__ float qEs[64][NDB];
  __shared__ float hist[4][16][NDB];
  __shared__ u16 Pt[4][16][40];
  __shared__ float Vsums[NDB][KHD];

  {
    const u16* vsrc = vtbf + ((size_t)(b * HH + h) * KHD) * LL;
    int r = tid >> 3, seg = tid & 7;
    const uint4* gs = (const uint4*)(vsrc + (size_t)r * LL);
    uint4* ls = (uint4*)(&Vt[r][0]);
#pragma unroll
    for (int j = 0; j < 8; ++j) ls[seg + j * 8] = gs[seg + j * 8];
  }
  {
    const float4* gs = (const float4*)(kE2 + (size_t)(b * HH + h) * LL * NDB);
    float4* ls = (float4*)(&kE2s[0][0]);
#pragma unroll
    for (int j = 0; j < 7; ++j) ls[tid + j * 256] = gs[tid + j * 256];
  }
  if (tid < 224) ((float4*)qEs)[tid] = ((const float4*)(qE2 + ((size_t)(b * HH + h) * LL + qt * 64) * NDB))[tid];
  if (tid < 112) ((float4*)Vsums)[tid] = ((const float4*)Vsum)[tid];
  if (tid < 224) { float4 zz = {0.f, 0.f, 0.f, 0.f}; ((float4*)hist)[tid] = zz; }

  const int row16 = qt * 64 + w * 16;
  const bf16x8 aQ = *(const bf16x8*)(qkv + ((size_t)(b * LL + row16 + lr)) * QKS + h * KHD + lg * 8);

  __syncthreads();

  f32x4 o0 = {0.f, 0.f, 0.f, 0.f}, o1 = {0.f, 0.f, 0.f, 0.f};
  const f32x4 zero4 = {0.f, 0.f, 0.f, 0.f};
  float mrow[4] = {-1e30f, -1e30f, -1e30f, -1e30f};
  float rsum[4] = {0.f, 0.f, 0.f, 0.f};

  const unsigned char* dbase = didx8 + (size_t)b * LL * LL;
  const u16* kbase = qkv + (size_t)b * LL * QKS + 512 + h * KHD + lg * 8;

  for (int ct = 0; ct < 16; ++ct) {
    const int x0 = ct * 32;
    bf16x8 bk0 = *(const bf16x8*)(kbase + (size_t)(x0 + lr) * QKS);
    bf16x8 bk1 = *(const bf16x8*)(kbase + (size_t)(x0 + 16 + lr) * QKS);
    f32x4 s0 = __builtin_amdgcn_mfma_f32_16x16x32_bf16(aQ, bk0, zero4, 0, 0, 0);
    f32x4 s1 = __builtin_amdgcn_mfma_f32_16x16x32_bf16(aQ, bk1, zero4, 0, 0, 0);

    float p0[4], p1[4], fac[4];
    int d0[4], d1[4];
#pragma unroll
    for (int i = 0; i < 4; ++i) {
      const int rl = lg * 4 + i;
      const int l = row16 + rl;
      const unsigned char* dr = dbase + (size_t)l * LL + x0;
      d0[i] = dr[lr];
      d1[i] = dr[16 + lr];
      float v0 = s0[i] + qEs[w * 16 + rl][d0[i]] + kE2s[x0 + lr][d0[i]];
      float v1 = s1[i] + qEs[w * 16 + rl][d1[i]] + kE2s[x0 + 16 + lr][d1[i]];
      float cm = fmaxf(v0, v1);
      cm = fmaxf(cm, __shfl_xor(cm, 1));
      cm = fmaxf(cm, __shfl_xor(cm, 2));
      cm = fmaxf(cm, __shfl_xor(cm, 4));
      cm = fmaxf(cm, __shfl_xor(cm, 8));
      float nm = fmaxf(mrow[i], cm);
      fac[i] = __expf(mrow[i] - nm);
      mrow[i] = nm;
      p0[i] = __expf(v0 - nm);
      p1[i] = __expf(v1 - nm);
      rsum[i] = rsum[i] * fac[i] + p0[i] + p1[i];
      o0[i] *= fac[i];
      o1[i] *= fac[i];
    }
    __syncthreads();
    if (lr < NDB) {
#pragma unroll
      for (int i = 0; i < 4; ++i) hist[w][lg * 4 + i][lr] *= fac[i];
    }
    __syncthreads();
#pragma unroll
    for (int i = 0; i < 4; ++i) {
      atomicAdd(&hist[w][lg * 4 + i][d0[i]], p0[i]);
      atomicAdd(&hist[w][lg * 4 + i][d1[i]], p1[i]);
      Pt[w][lg * 4 + i][lr] = f2bf(p0[i]);
      Pt[w][lg * 4 + i][16 + lr] = f2bf(p1[i]);
    }
    __syncthreads();
    bf16x8 aP = *(const bf16x8*)(&Pt[w][lr][lg * 8]);
    bf16x8 vb0 = *(const bf16x8*)(&Vt[lr][x0 + lg * 8]);
    bf16x8 vb1 = *(const bf16x8*)(&Vt[16 + lr][x0 + lg * 8]);
    o0 = __builtin_amdgcn_mfma_f32_16x16x32_bf16(aP, vb0, o0, 0, 0, 0);
    o1 = __builtin_amdgcn_mfma_f32_16x16x32_bf16(aP, vb1, o1, 0, 0, 0);
  }

  __syncthreads();
#pragma unroll
  for (int i = 0; i < 4; ++i) {
    float s = rsum[i];
    s += __shfl_xor(s, 1);
    s += __shfl_xor(s, 2);
    s += __shfl_xor(s, 4);
    s += __shfl_xor(s, 8);
    const float inv = 1.0f / s;
    float b0 = 0.f, b1 = 0.f;
#pragma unroll
    for (int d = 0; d < NDB; ++d) {
      float a = hist[w][lg * 4 + i][d];
      b0 += a * Vsums[d][lr];
      b1 += a * Vsums[d][16 + lr];
    }
    const size_t orow = ((size_t)(b * LL + row16 + lg * 4 + i)) * DDIM + h * KHD;
    z[orow + lr] = f2bf((o0[i] + b0) * inv);
    z[orow + 16 + lr] = f2bf((o1[i] + b1) * inv);
  }
}

// ---------------- out = LN(X + Y), f32 + bf16 ----------------
__global__ __launch_bounds__(256) void add_ln_kernel(
    const float* __restrict__ X, const float* __restrict__ Y,
    const float* __restrict__ g, const float* __restrict__ be,
    float* __restrict__ out, u16* __restrict__ outb) {
  const int row = blockIdx.x, tid = threadIdx.x;
  const int lane = tid & 63, wid = tid >> 6;
  __shared__ float red[4];
  const size_t base = (size_t)row * DDIM;
  float x0 = X[base + tid] + Y[base + tid];
  float x1 = X[base + tid + 256] + Y[base + tid + 256];
  float s = wredSum(x0 + x1);
  if (lane == 0) red[wid] = s;
  __syncthreads();
  float mu = (red[0] + red[1] + red[2] + red[3]) * (1.0f / DDIM);
  __syncthreads();
  float d0 = x0 - mu, d1 = x1 - mu;
  float vs = wredSum(d0 * d0 + d1 * d1);
  if (lane == 0) red[wid] = vs;
  __syncthreads();
  float var = (red[0] + red[1] + red[2] + red[3]) * (1.0f / DDIM);
  float inv = rsqrtf(var + 1e-5f);
  float r0 = d0 * inv * g[tid] + be[tid];
  float r1 = d1 * inv * g[tid + 256] + be[tid + 256];
  out[base + tid] = r0;
  out[base + tid + 256] = r1;
  outb[base + tid] = f2bf(r0);
  outb[base + tid + 256] = f2bf(r1);
}

// ---------------- pooled[b,d] = sum_l h[b,l,d] ----------------
__global__ void pool_kernel(const float* __restrict__ h, float* __restrict__ pooled, int n) {
  int i = blockIdx.x * 256 + threadIdx.x;
  if (i >= n) return;
  int b = i >> 9, d = i & 511;
  float s = 0.f;
  for (int l = 0; l < LL; ++l) s += h[(size_t)(b * LL + l) * DDIM + d];
  pooled[i] = s;
}

// ---------------- head ----------------
__global__ __launch_bounds__(256) void head_kernel(
    const float* __restrict__ pooled, const float* __restrict__ Wm1,
    const float* __restrict__ bm1, const float* __restrict__ Wm2,
    const float* __restrict__ bm2, float* __restrict__ out) {
  int b = blockIdx.x, tid = threadIdx.x;
  const float* p = pooled + b * DDIM;
  float part = 0.f;
  for (int jj = 0; jj < 2; ++jj) {
    int j = tid + jj * 256;
    float s = bm1[j];
    for (int dd = 0; dd < DDIM; ++dd) s += p[dd] * Wm1[(size_t)dd * MMD + j];
    part += fmaxf(s, 0.f) * Wm2[j];
  }
  __shared__ float red[4];
  int lane = tid & 63, wid = tid >> 6;
  float ssum = wredSum(part);
  if (lane == 0) red[wid] = ssum;
  __syncthreads();
  if (tid == 0) out[b] = red[0] + red[1] + red[2] + red[3] + bm2[0];
}

extern "C" void kernel_launch(void* const* d_in, const int* in_sizes, int n_in,
                              void* d_out, int out_size, void* d_ws, size_t ws_size,
                              hipStream_t stream) {
  const int* cell_types = (const int*)d_in[0];
  const float* distances = (const float*)d_in[1];
  const float* cell_emb = (const float*)d_in[2];
  const float* Kqk = (const float*)d_in[3];
  const float* Kqr = (const float*)d_in[4];
  const float* Kkr = (const float*)d_in[5];
  const float* Vqk = (const float*)d_in[6];
  const float* Vqr = (const float*)d_in[7];
  const float* Vkr = (const float*)d_in[8];
  const float* Wq = (const float*)d_in[9];
  const float* Wk = (const float*)d_in[10];
  const float* Wv = (const float*)d_in[11];
  const float* Wo = (const float*)d_in[12];
  const float* bq = (const float*)d_in[13];
  const float* bk = (const float*)d_in[14];
  const float* bv = (const float*)d_in[15];
  const float* bo = (const float*)d_in[16];
  const float* W1 = (const float*)d_in[17];
  const float* b1 = (const float*)d_in[18];
  const float* W2 = (const float*)d_in[19];
  const float* b2 = (const float*)d_in[20];
  const float* g1 = (const float*)d_in[21];
  const float* be1 = (const float*)d_in[22];
  const float* g2 = (const float*)d_in[23];
  const float* be2 = (const float*)d_in[24];
  const float* Wm1 = (const float*)d_in[25];
  const float* bm1 = (const float*)d_in[26];
  const float* Wm2 = (const float*)d_in[27];
  const float* bm2 = (const float*)d_in[28];

  char* w = (char*)d_ws;
  auto alloc = [&](size_t bytes) { void* p = (void*)w; w += (bytes + 255) & ~(size_t)255; return p; };
  unsigned char* didx8 = (unsigned char*)alloc(sizeof(unsigned char) * BB * LL * LL);
  float* h    = (float*)alloc(sizeof(float) * BB * LL * DDIM);
  u16* hbf    = (u16*)alloc(sizeof(u16) * BB * LL * DDIM);
  float* h2   = (float*)alloc(sizeof(float) * BB * LL * DDIM);
  u16* h2bf   = (u16*)alloc(sizeof(u16) * BB * LL * DDIM);
  u16* qkvbf  = (u16*)alloc(sizeof(u16) * BB * LL * QKS);
  float* ob   = (float*)alloc(sizeof(float) * BB * LL * DDIM);   // O out, reused as FF2 out
  u16* f1bf   = (u16*)alloc(sizeof(u16) * BB * LL * FFD);
  u16* zbf    = (u16*)alloc(sizeof(u16) * BB * LL * DDIM);
  u16* vtbf   = (u16*)alloc(sizeof(u16) * BB * HH * KHD * LL);
  float* qE2  = (float*)alloc(sizeof(float) * BB * HH * LL * NDB);
  float* kE2  = (float*)alloc(sizeof(float) * BB * HH * LL * NDB);
  u16* Wqkvt  = (u16*)alloc(sizeof(u16) * QKS * DDIM);
  u16* Wot    = (u16*)alloc(sizeof(u16) * DDIM * DDIM);
  u16* W1t    = (u16*)alloc(sizeof(u16) * FFD * DDIM);
  u16* W2t    = (u16*)alloc(sizeof(u16) * DDIM * FFD);
  float* bqkv = (float*)alloc(sizeof(float) * NLAY * QKS);
  float* Vsum = (float*)alloc(sizeof(float) * NDB * KHD);
  float* EkrS = (float*)alloc(sizeof(float) * NDB);
  float* pooled = (float*)alloc(sizeof(float) * BB * DDIM);

  const int Mrows = BB * LL;

  bucketize_kernel<<<(BB * LL * LL + 255) / 256, 256, 0, stream>>>(distances, didx8, BB * LL * LL);
  embed_kernel<<<(BB * LL * DDIM + 255) / 256, 256, 0, stream>>>(cell_types, cell_emb, h, hbf, BB * LL * DDIM);
  prep_kernel<<<1, 512, 0, stream>>>(Vqk, Vqr, Vkr, Kkr, Vsum, EkrS);
  biaspack_kernel<<<(NLAY * QKS + 255) / 256, 256, 0, stream>>>(bq, bk, bv, bqkv);

  const int nrel = BB * HH * LL * NDB;

  for (int lay = 0; lay < NLAY; ++lay) {
    wconv_layer<<<768, 256, 0, stream>>>(
        Wq + (size_t)lay * DDIM * DDIM, Wk + (size_t)lay * DDIM * DDIM,
        Wv + (size_t)lay * DDIM * DDIM, Wo + (size_t)lay * DDIM * DDIM,
        W1 + (size_t)lay * DDIM * FFD, W2 + (size_t)lay * FFD * DDIM,
        Wqkvt, Wot, W1t, W2t);

    // fused QKV: [2048,512] @ [512,1536] -> packed bf16 (q scaled)
    gemm_bf16<<<dim3(QKS / 128, Mrows / 64), 256, 0, stream>>>(
        hbf, Wqkvt, bqkv + (size_t)lay * QKS, nullptr, qkvbf, Mrows, QKS, DDIM, 0, 512);

    proj_relbf_kernel<<<(nrel + 255) / 256, 256, 0, stream>>>(qkvbf, Kqk, nullptr, 1.0f, qE2);
    proj_relbf_kernel<<<(nrel + 255) / 256, 256, 0, stream>>>(qkvbf + 512, Kqr, EkrS, SCALEF, kE2);
    vtrans_kernel<<<dim3(HH, BB), 256, 0, stream>>>(qkvbf, vtbf);
    attn2_kernel<<<dim3(8, HH, BB), 256, 0, stream>>>(qkvbf, vtbf, qE2, kE2, didx8, Vsum, zbf);

    gemm_bf16<<<dim3(DDIM / 128, Mrows / 64), 256, 0, stream>>>(
        zbf, Wot, bo + (size_t)lay * DDIM, ob, nullptr, Mrows, DDIM, DDIM, 0, 0);
    add_ln_kernel<<<Mrows, 256, 0, stream>>>(h, ob, g1 + (size_t)lay * DDIM, be1 + (size_t)lay * DDIM, h2, h2bf);
    gemm_bf16<<<dim3(FFD / 128, Mrows / 64), 256, 0, stream>>>(
        h2bf, W1t, b1 + (size_t)lay * FFD, nullptr, f1bf, Mrows, FFD, DDIM, 1, 0);
    gemm_bf16<<<dim3(DDIM / 128, Mrows / 64), 256, 0, stream>>>(
        f1bf, W2t, b2 + (size_t)lay * DDIM, ob, nullptr, Mrows, DDIM, FFD, 0, 0);
    add_ln_kernel<<<Mrows, 256, 0, stream>>>(h2, ob, g2 + (size_t)lay * DDIM, be2 + (size_t)lay * DDIM, h, hbf);
  }

  pool_kernel<<<(BB * DDIM + 255) / 256, 256, 0, stream>>>(h, pooled, BB * DDIM);
  head_kernel<<<BB, 256, 0, stream>>>(pooled, Wm1, bm1, Wm2, bm2, (float*)d_out);
}

// Round 4
// 1739.438 us; speedup vs baseline: 3.5480x; 1.0541x over previous
//
#include <hip/hip_runtime.h>
#include <math.h>

#define NLAY 8
#define BB 4
#define LL 512
#define DDIM 512
#define HH 16
#define KHD 32
#define FFD 2048
#define MMD 512
#define NDB 14
#define QKS 1536
#define SCALEF 0.17677669529663687f

typedef unsigned short u16;
typedef __attribute__((ext_vector_type(8))) short bf16x8;
typedef __attribute__((ext_vector_type(4))) float f32x4;

__device__ __forceinline__ u16 f2bf(float f) {
  unsigned u = __builtin_bit_cast(unsigned, f);
  u = (u + 0x7fffu + ((u >> 16) & 1u)) >> 16;
  return (u16)u;
}
__device__ __forceinline__ float bf2f(u16 v) {
  unsigned u = ((unsigned)v) << 16;
  return __builtin_bit_cast(float, u);
}
__device__ __forceinline__ float wredSum(float v) {
#pragma unroll
  for (int o = 32; o > 0; o >>= 1) v += __shfl_down(v, o);
  return v;
}
__device__ __forceinline__ void gload_lds16(const u16* g, u16* l) {
  __builtin_amdgcn_global_load_lds((const __attribute__((address_space(1))) void*)g,
                                   (__attribute__((address_space(3))) void*)l, 16, 0, 0);
}

// ---------------- bucketize -> uint8 ----------------
__global__ void bucketize_kernel(const float* __restrict__ dist, unsigned char* __restrict__ didx, int n) {
  int i = blockIdx.x * 256 + threadIdx.x;
  if (i >= n) return;
  float d = dist[i];
  int c = 0;
#pragma unroll
  for (int t = 1; t <= NDB; ++t) c += (10.0f * (float)t < d) ? 1 : 0;
  didx[i] = (unsigned char)(c > (NDB - 1) ? (NDB - 1) : c);
}

// ---------------- h = cell_emb[cell_types] (f32 + bf16) ----------------
__global__ void embed_kernel(const int* __restrict__ ct, const float* __restrict__ emb,
                             float* __restrict__ h, u16* __restrict__ hbf, int n) {
  int i = blockIdx.x * 256 + threadIdx.x;
  if (i >= n) return;
  int bl = i >> 9, d = i & 511;
  float v = emb[ct[bl] * DDIM + d];
  h[i] = v;
  hbf[i] = f2bf(v);
}

// ---------------- Vsum, EkrS ----------------
__global__ void prep_kernel(const float* __restrict__ Vqk, const float* __restrict__ Vqr,
                            const float* __restrict__ Vkr, const float* __restrict__ Kkr,
                            float* __restrict__ Vsum, float* __restrict__ EkrS) {
  int tid = threadIdx.x;
  if (tid < NDB * KHD) Vsum[tid] = Vqk[tid] + Vqr[tid] + Vkr[tid];
  if (tid < NDB) {
    float s = 0.f;
    for (int kk = 0; kk < KHD; ++kk) s += Kkr[tid * KHD + kk];
    EkrS[tid] = s;
  }
}

// ---------------- packed qkv bias [NLAY][1536] ----------------
__global__ void biaspack_kernel(const float* __restrict__ bq, const float* __restrict__ bk,
                                const float* __restrict__ bv, float* __restrict__ bqkv) {
  int i = blockIdx.x * 256 + threadIdx.x;
  if (i >= NLAY * QKS) return;
  int lay = i / QKS, c = i % QKS;
  float v;
  if (c < 512) v = bq[lay * DDIM + c];
  else if (c < 1024) v = bk[lay * DDIM + c - 512];
  else v = bv[lay * DDIM + c - 1024];
  bqkv[i] = v;
}

// ---------------- per-layer weight transpose+convert: src f32 [K,N] -> dst bf16 [N,K] ----------------
__device__ __forceinline__ void wtconv_tile(const float* __restrict__ src, u16* __restrict__ dst,
                                            int K, int N, int tn, int tk) {
  __shared__ float tl[64][65];
  const int t = threadIdx.x;
#pragma unroll
  for (int p = 0; p < 4; ++p) {
    int k = tk * 64 + p * 16 + (t >> 4);
    int n = tn * 64 + (t & 15) * 4;
    float4 v = *(const float4*)(src + (size_t)k * N + n);
    tl[(t & 15) * 4 + 0][p * 16 + (t >> 4)] = v.x;
    tl[(t & 15) * 4 + 1][p * 16 + (t >> 4)] = v.y;
    tl[(t & 15) * 4 + 2][p * 16 + (t >> 4)] = v.z;
    tl[(t & 15) * 4 + 3][p * 16 + (t >> 4)] = v.w;
  }
  __syncthreads();
  int n = t >> 2, cc = t & 3;
  u16 o[16];
#pragma unroll
  for (int e = 0; e < 16; ++e) o[e] = f2bf(tl[n][cc * 16 + e]);
  u16* dp = dst + (size_t)(tn * 64 + n) * K + tk * 64 + cc * 16;
  *(uint4*)(dp) = *(uint4*)&o[0];
  *(uint4*)(dp + 8) = *(uint4*)&o[8];
}

__global__ __launch_bounds__(256) void wconv_layer(
    const float* __restrict__ Wq, const float* __restrict__ Wk, const float* __restrict__ Wv,
    const float* __restrict__ Wo, const float* __restrict__ W1, const float* __restrict__ W2,
    u16* __restrict__ Wqkvt, u16* __restrict__ Wot, u16* __restrict__ W1t, u16* __restrict__ W2t) {
  int b = blockIdx.x;
  if (b < 64) { wtconv_tile(Wq, Wqkvt, 512, 512, b >> 3, b & 7); return; }
  if (b < 128) { b -= 64; wtconv_tile(Wk, Wqkvt + 512 * 512, 512, 512, b >> 3, b & 7); return; }
  if (b < 192) { b -= 128; wtconv_tile(Wv, Wqkvt + 1024 * 512, 512, 512, b >> 3, b & 7); return; }
  if (b < 256) { b -= 192; wtconv_tile(Wo, Wot, 512, 512, b >> 3, b & 7); return; }
  if (b < 512) { b -= 256; wtconv_tile(W1, W1t, 512, FFD, b >> 3, b & 7); return; }
  b -= 512; wtconv_tile(W2, W2t, FFD, 512, b >> 5, b & 31);
}

// ---------------- bf16 MFMA GEMM: C = A[M,K]bf16 @ Bt[N,K]bf16^T + bias ----------------
__global__ __launch_bounds__(256) void gemm_bf16(
    const u16* __restrict__ A, const u16* __restrict__ Bt, const float* __restrict__ bias,
    float* __restrict__ Cf, u16* __restrict__ Cb,
    int M, int N, int K, int act, int scaleLT) {
  __shared__ u16 As[64 * 64];
  __shared__ u16 Bs[128 * 64];
  const int tid = threadIdx.x, w = tid >> 6, lane = tid & 63;
  const int lr = lane & 15, lg = lane >> 4;
  const int row0 = blockIdx.y * 64, col0 = blockIdx.x * 128;
  const int srow = lane >> 3;
  const int aoff = ((lane & 7) ^ srow) * 8;
  const f32x4 z4 = {0.f, 0.f, 0.f, 0.f};
  f32x4 acc[4][2];
#pragma unroll
  for (int mi = 0; mi < 4; ++mi)
#pragma unroll
    for (int ni = 0; ni < 2; ++ni) acc[mi][ni] = z4;

  const int nw = w * 32;
  for (int k0 = 0; k0 < K; k0 += 64) {
#pragma unroll
    for (int i = 0; i < 2; ++i)
      gload_lds16(A + (size_t)(row0 + w * 16 + i * 8 + srow) * K + k0 + aoff,
                  As + (w * 16 + i * 8) * 64);
#pragma unroll
    for (int i = 0; i < 4; ++i)
      gload_lds16(Bt + (size_t)(col0 + w * 32 + i * 8 + srow) * K + k0 + aoff,
                  Bs + (w * 32 + i * 8) * 64);
    __syncthreads();
#pragma unroll
    for (int kh = 0; kh < 2; ++kh) {
      bf16x8 a[4], b[2];
#pragma unroll
      for (int mi = 0; mi < 4; ++mi) {
        int r = mi * 16 + lr;
        a[mi] = *(const bf16x8*)(As + r * 64 + (((kh * 4 + lg) ^ (r & 7)) << 3));
      }
#pragma unroll
      for (int ni = 0; ni < 2; ++ni) {
        int r = nw + ni * 16 + lr;
        b[ni] = *(const bf16x8*)(Bs + r * 64 + (((kh * 4 + lg) ^ (r & 7)) << 3));
      }
#pragma unroll
      for (int mi = 0; mi < 4; ++mi)
#pragma unroll
        for (int ni = 0; ni < 2; ++ni)
          acc[mi][ni] = __builtin_amdgcn_mfma_f32_16x16x32_bf16(a[mi], b[ni], acc[mi][ni], 0, 0, 0);
    }
    __syncthreads();
  }
#pragma unroll
  for (int mi = 0; mi < 4; ++mi) {
    int r = row0 + mi * 16 + lg * 4;
#pragma unroll
    for (int ni = 0; ni < 2; ++ni) {
      int c = col0 + nw + ni * 16 + lr;
      float bs = bias[c];
      float sc = (c < scaleLT) ? SCALEF : 1.0f;
#pragma unroll
      for (int j = 0; j < 4; ++j) {
        float v = acc[mi][ni][j] + bs;
        if (act == 1) v = 0.5f * v * (1.0f + erff(v * 0.70710678118654752f));
        size_t idx = (size_t)(r + j) * N + c;
        if (Cf) Cf[idx] = v;
        if (Cb) Cb[idx] = f2bf(v * sc);
      }
    }
  }
}

// ---------------- rel projection from packed bf16 qkv ----------------
__global__ void proj_relbf_kernel(const u16* __restrict__ x, const float* __restrict__ Kr,
                                  const float* __restrict__ ekrs, float scale_mul,
                                  float* __restrict__ outp) {
  int idx = blockIdx.x * 256 + threadIdx.x;
  if (idx >= BB * HH * LL * NDB) return;
  int d = idx % NDB;
  int rest = idx / NDB;
  int l = rest & (LL - 1);
  int bh = rest >> 9;
  int h = bh & (HH - 1);
  int b = bh >> 4;
  const u16* xr = x + ((size_t)(b * LL + l)) * QKS + h * KHD;
  const float* kr = Kr + d * KHD;
  float s = 0.f;
#pragma unroll
  for (int kk = 0; kk < KHD; ++kk) s += bf2f(xr[kk]) * kr[kk];
  s *= scale_mul;
  if (ekrs) s += SCALEF * ekrs[d];
  outp[idx] = s;
}

// ---------------- v (packed bf16 cols 1024..1535) -> vt [b,h,kh,x] bf16 ----------------
__global__ __launch_bounds__(256) void vtrans_kernel(const u16* __restrict__ qkv, u16* __restrict__ vt) {
  const int h = blockIdx.x, b = blockIdx.y, tid = threadIdx.x;
  __shared__ u16 tile[KHD][520];
  for (int it = 0; it < 64; ++it) {
    int idx = it * 256 + tid;
    int x = idx >> 5, kh = idx & 31;
    tile[kh][x] = qkv[((size_t)(b * LL) + x) * QKS + 1024 + h * KHD + kh];
  }
  __syncthreads();
  int r = tid >> 3, seg = tid & 7;
  uint4* dst = (uint4*)(vt + ((size_t)(b * HH + h) * KHD + r) * LL);
  const uint4* src = (const uint4*)(&tile[r][0]);
#pragma unroll
  for (int j = 0; j < 8; ++j) dst[seg + j * 8] = src[seg + j * 8];
}

// ---------------- flash attention with MFMA — barrier-free chunk loop, no-max softmax ----------------
// hist/Pt are PER-WAVE arrays: same-wave LDS ordering makes all in-loop __syncthreads unnecessary.
// Scores are LN-bounded (|v| < ~10), so exp without max-subtraction is exact softmax, overflow-safe.
__global__ __launch_bounds__(256) void attn2_kernel(
    const u16* __restrict__ qkv, const u16* __restrict__ vtbf, const float* __restrict__ qE2,
    const float* __restrict__ kE2, const unsigned char* __restrict__ didx8,
    const float* __restrict__ Vsum, u16* __restrict__ z) {
  const int qt = blockIdx.x, h = blockIdx.y, b = blockIdx.z;
  const int tid = threadIdx.x, lane = tid & 63, w = tid >> 6;
  const int lr = lane & 15, lg = lane >> 4;

  __shared__ u16 Vt[KHD][520];
  __shared__ float kE2s[LL][NDB];
  __shared__ float qEs[64][NDB];
  __shared__ float hist[4][16][NDB];
  __shared__ u16 Pt[4][16][40];
  __shared__ float Vsums[NDB][KHD];

  {
    const u16* vsrc = vtbf + ((size_t)(b * HH + h) * KHD) * LL;
    int r = tid >> 3, seg = tid & 7;
    const uint4* gs = (const uint4*)(vsrc + (size_t)r * LL);
    uint4* ls = (uint4*)(&Vt[r][0]);
#pragma unroll
    for (int j = 0; j < 8; ++j) ls[seg + j * 8] = gs[seg + j * 8];
  }
  {
    const float4* gs = (const float4*)(kE2 + (size_t)(b * HH + h) * LL * NDB);
    float4* ls = (float4*)(&kE2s[0][0]);
#pragma unroll
    for (int j = 0; j < 7; ++j) ls[tid + j * 256] = gs[tid + j * 256];
  }
  if (tid < 224) ((float4*)qEs)[tid] = ((const float4*)(qE2 + ((size_t)(b * HH + h) * LL + qt * 64) * NDB))[tid];
  if (tid < 112) ((float4*)Vsums)[tid] = ((const float4*)Vsum)[tid];
  if (tid < 224) { float4 zz = {0.f, 0.f, 0.f, 0.f}; ((float4*)hist)[tid] = zz; }

  const int row16 = qt * 64 + w * 16;
  const bf16x8 aQ = *(const bf16x8*)(qkv + ((size_t)(b * LL + row16 + lr)) * QKS + h * KHD + lg * 8);

  __syncthreads();  // the ONLY block-wide barrier: staging complete

  f32x4 o0 = {0.f, 0.f, 0.f, 0.f}, o1 = {0.f, 0.f, 0.f, 0.f};
  const f32x4 zero4 = {0.f, 0.f, 0.f, 0.f};
  float rsum[4] = {0.f, 0.f, 0.f, 0.f};

  const unsigned char* dbase = didx8 + (size_t)b * LL * LL + (size_t)row16 * LL;
  const u16* kbase = qkv + (size_t)b * LL * QKS + 512 + h * KHD + lg * 8;

  for (int ct = 0; ct < 16; ++ct) {
    const int x0 = ct * 32;
    bf16x8 bk0 = *(const bf16x8*)(kbase + (size_t)(x0 + lr) * QKS);
    bf16x8 bk1 = *(const bf16x8*)(kbase + (size_t)(x0 + 16 + lr) * QKS);
    f32x4 s0 = __builtin_amdgcn_mfma_f32_16x16x32_bf16(aQ, bk0, zero4, 0, 0, 0);
    f32x4 s1 = __builtin_amdgcn_mfma_f32_16x16x32_bf16(aQ, bk1, zero4, 0, 0, 0);

#pragma unroll
    for (int i = 0; i < 4; ++i) {
      const int rl = lg * 4 + i;
      const unsigned char* dr = dbase + (size_t)rl * LL + x0;
      const int d0 = dr[lr];
      const int d1 = dr[16 + lr];
      float v0 = s0[i] + qEs[w * 16 + rl][d0] + kE2s[x0 + lr][d0];
      float v1 = s1[i] + qEs[w * 16 + rl][d1] + kE2s[x0 + 16 + lr][d1];
      float p0 = __expf(v0);
      float p1 = __expf(v1);
      rsum[i] += p0 + p1;
      atomicAdd(&hist[w][rl][d0], p0);
      atomicAdd(&hist[w][rl][d1], p1);
      Pt[w][rl][lr] = f2bf(p0);
      Pt[w][rl][16 + lr] = f2bf(p1);
    }
    // per-wave LDS ordering: Pt writes above complete (in wave program order)
    // before the reads below; compiler inserts the lgkmcnt waits.
    bf16x8 aP = *(const bf16x8*)(&Pt[w][lr][lg * 8]);
    bf16x8 vb0 = *(const bf16x8*)(&Vt[lr][x0 + lg * 8]);
    bf16x8 vb1 = *(const bf16x8*)(&Vt[16 + lr][x0 + lg * 8]);
    o0 = __builtin_amdgcn_mfma_f32_16x16x32_bf16(aP, vb0, o0, 0, 0, 0);
    o1 = __builtin_amdgcn_mfma_f32_16x16x32_bf16(aP, vb1, o1, 0, 0, 0);
  }

#pragma unroll
  for (int i = 0; i < 4; ++i) {
    float s = rsum[i];
    s += __shfl_xor(s, 1);
    s += __shfl_xor(s, 2);
    s += __shfl_xor(s, 4);
    s += __shfl_xor(s, 8);
    const float inv = 1.0f / s;
    float b0 = 0.f, b1 = 0.f;
#pragma unroll
    for (int d = 0; d < NDB; ++d) {
      float a = hist[w][lg * 4 + i][d];
      b0 += a * Vsums[d][lr];
      b1 += a * Vsums[d][16 + lr];
    }
    const size_t orow = ((size_t)(b * LL + row16 + lg * 4 + i)) * DDIM + h * KHD;
    z[orow + lr] = f2bf((o0[i] + b0) * inv);
    z[orow + 16 + lr] = f2bf((o1[i] + b1) * inv);
  }
}

// ---------------- out = LN(X + Y), f32 + bf16 ----------------
__global__ __launch_bounds__(256) void add_ln_kernel(
    const float* __restrict__ X, const float* __restrict__ Y,
    const float* __restrict__ g, const float* __restrict__ be,
    float* __restrict__ out, u16* __restrict__ outb) {
  const int row = blockIdx.x, tid = threadIdx.x;
  const int lane = tid & 63, wid = tid >> 6;
  __shared__ float red[4];
  const size_t base = (size_t)row * DDIM;
  float x0 = X[base + tid] + Y[base + tid];
  float x1 = X[base + tid + 256] + Y[base + tid + 256];
  float s = wredSum(x0 + x1);
  if (lane == 0) red[wid] = s;
  __syncthreads();
  float mu = (red[0] + red[1] + red[2] + red[3]) * (1.0f / DDIM);
  __syncthreads();
  float d0 = x0 - mu, d1 = x1 - mu;
  float vs = wredSum(d0 * d0 + d1 * d1);
  if (lane == 0) red[wid] = vs;
  __syncthreads();
  float var = (red[0] + red[1] + red[2] + red[3]) * (1.0f / DDIM);
  float inv = rsqrtf(var + 1e-5f);
  float r0 = d0 * inv * g[tid] + be[tid];
  float r1 = d1 * inv * g[tid + 256] + be[tid + 256];
  out[base + tid] = r0;
  out[base + tid + 256] = r1;
  outb[base + tid] = f2bf(r0);
  outb[base + tid + 256] = f2bf(r1);
}

// ---------------- pooled[b,d] = sum_l h[b,l,d] ----------------
__global__ void pool_kernel(const float* __restrict__ h, float* __restrict__ pooled, int n) {
  int i = blockIdx.x * 256 + threadIdx.x;
  if (i >= n) return;
  int b = i >> 9, d = i & 511;
  float s = 0.f;
  for (int l = 0; l < LL; ++l) s += h[(size_t)(b * LL + l) * DDIM + d];
  pooled[i] = s;
}

// ---------------- head ----------------
__global__ __launch_bounds__(256) void head_kernel(
    const float* __restrict__ pooled, const float* __restrict__ Wm1,
    const float* __restrict__ bm1, const float* __restrict__ Wm2,
    const float* __restrict__ bm2, float* __restrict__ out) {
  int b = blockIdx.x, tid = threadIdx.x;
  const float* p = pooled + b * DDIM;
  float part = 0.f;
  for (int jj = 0; jj < 2; ++jj) {
    int j = tid + jj * 256;
    float s = bm1[j];
    for (int dd = 0; dd < DDIM; ++dd) s += p[dd] * Wm1[(size_t)dd * MMD + j];
    part += fmaxf(s, 0.f) * Wm2[j];
  }
  __shared__ float red[4];
  int lane = tid & 63, wid = tid >> 6;
  float ssum = wredSum(part);
  if (lane == 0) red[wid] = ssum;
  __syncthreads();
  if (tid == 0) out[b] = red[0] + red[1] + red[2] + red[3] + bm2[0];
}

extern "C" void kernel_launch(void* const* d_in, const int* in_sizes, int n_in,
                              void* d_out, int out_size, void* d_ws, size_t ws_size,
                              hipStream_t stream) {
  const int* cell_types = (const int*)d_in[0];
  const float* distances = (const float*)d_in[1];
  const float* cell_emb = (const float*)d_in[2];
  const float* Kqk = (const float*)d_in[3];
  const float* Kqr = (const float*)d_in[4];
  const float* Kkr = (const float*)d_in[5];
  const float* Vqk = (const float*)d_in[6];
  const float* Vqr = (const float*)d_in[7];
  const float* Vkr = (const float*)d_in[8];
  const float* Wq = (const float*)d_in[9];
  const float* Wk = (const float*)d_in[10];
  const float* Wv = (const float*)d_in[11];
  const float* Wo = (const float*)d_in[12];
  const float* bq = (const float*)d_in[13];
  const float* bk = (const float*)d_in[14];
  const float* bv = (const float*)d_in[15];
  const float* bo = (const float*)d_in[16];
  const float* W1 = (const float*)d_in[17];
  const float* b1 = (const float*)d_in[18];
  const float* W2 = (const float*)d_in[19];
  const float* b2 = (const float*)d_in[20];
  const float* g1 = (const float*)d_in[21];
  const float* be1 = (const float*)d_in[22];
  const float* g2 = (const float*)d_in[23];
  const float* be2 = (const float*)d_in[24];
  const float* Wm1 = (const float*)d_in[25];
  const float* bm1 = (const float*)d_in[26];
  const float* Wm2 = (const float*)d_in[27];
  const float* bm2 = (const float*)d_in[28];

  char* w = (char*)d_ws;
  auto alloc = [&](size_t bytes) { void* p = (void*)w; w += (bytes + 255) & ~(size_t)255; return p; };
  unsigned char* didx8 = (unsigned char*)alloc(sizeof(unsigned char) * BB * LL * LL);
  float* h    = (float*)alloc(sizeof(float) * BB * LL * DDIM);
  u16* hbf    = (u16*)alloc(sizeof(u16) * BB * LL * DDIM);
  float* h2   = (float*)alloc(sizeof(float) * BB * LL * DDIM);
  u16* h2bf   = (u16*)alloc(sizeof(u16) * BB * LL * DDIM);
  u16* qkvbf  = (u16*)alloc(sizeof(u16) * BB * LL * QKS);
  float* ob   = (float*)alloc(sizeof(float) * BB * LL * DDIM);
  u16* f1bf   = (u16*)alloc(sizeof(u16) * BB * LL * FFD);
  u16* zbf    = (u16*)alloc(sizeof(u16) * BB * LL * DDIM);
  u16* vtbf   = (u16*)alloc(sizeof(u16) * BB * HH * KHD * LL);
  float* qE2  = (float*)alloc(sizeof(float) * BB * HH * LL * NDB);
  float* kE2  = (float*)alloc(sizeof(float) * BB * HH * LL * NDB);
  u16* Wqkvt  = (u16*)alloc(sizeof(u16) * QKS * DDIM);
  u16* Wot    = (u16*)alloc(sizeof(u16) * DDIM * DDIM);
  u16* W1t    = (u16*)alloc(sizeof(u16) * FFD * DDIM);
  u16* W2t    = (u16*)alloc(sizeof(u16) * DDIM * FFD);
  float* bqkv = (float*)alloc(sizeof(float) * NLAY * QKS);
  float* Vsum = (float*)alloc(sizeof(float) * NDB * KHD);
  float* EkrS = (float*)alloc(sizeof(float) * NDB);
  float* pooled = (float*)alloc(sizeof(float) * BB * DDIM);

  const int Mrows = BB * LL;

  bucketize_kernel<<<(BB * LL * LL + 255) / 256, 256, 0, stream>>>(distances, didx8, BB * LL * LL);
  embed_kernel<<<(BB * LL * DDIM + 255) / 256, 256, 0, stream>>>(cell_types, cell_emb, h, hbf, BB * LL * DDIM);
  prep_kernel<<<1, 512, 0, stream>>>(Vqk, Vqr, Vkr, Kkr, Vsum, EkrS);
  biaspack_kernel<<<(NLAY * QKS + 255) / 256, 256, 0, stream>>>(bq, bk, bv, bqkv);

  const int nrel = BB * HH * LL * NDB;

  for (int lay = 0; lay < NLAY; ++lay) {
    wconv_layer<<<768, 256, 0, stream>>>(
        Wq + (size_t)lay * DDIM * DDIM, Wk + (size_t)lay * DDIM * DDIM,
        Wv + (size_t)lay * DDIM * DDIM, Wo + (size_t)lay * DDIM * DDIM,
        W1 + (size_t)lay * DDIM * FFD, W2 + (size_t)lay * FFD * DDIM,
        Wqkvt, Wot, W1t, W2t);

    gemm_bf16<<<dim3(QKS / 128, Mrows / 64), 256, 0, stream>>>(
        hbf, Wqkvt, bqkv + (size_t)lay * QKS, nullptr, qkvbf, Mrows, QKS, DDIM, 0, 512);

    proj_relbf_kernel<<<(nrel + 255) / 256, 256, 0, stream>>>(qkvbf, Kqk, nullptr, 1.0f, qE2);
    proj_relbf_kernel<<<(nrel + 255) / 256, 256, 0, stream>>>(qkvbf + 512, Kqr, EkrS, SCALEF, kE2);
    vtrans_kernel<<<dim3(HH, BB), 256, 0, stream>>>(qkvbf, vtbf);
    attn2_kernel<<<dim3(8, HH, BB), 256, 0, stream>>>(qkvbf, vtbf, qE2, kE2, didx8, Vsum, zbf);

    gemm_bf16<<<dim3(DDIM / 128, Mrows / 64), 256, 0, stream>>>(
        zbf, Wot, bo + (size_t)lay * DDIM, ob, nullptr, Mrows, DDIM, DDIM, 0, 0);
    add_ln_kernel<<<Mrows, 256, 0, stream>>>(h, ob, g1 + (size_t)lay * DDIM, be1 + (size_t)lay * DDIM, h2, h2bf);
    gemm_bf16<<<dim3(FFD / 128, Mrows / 64), 256, 0, stream>>>(
        h2bf, W1t, b1 + (size_t)lay * FFD, nullptr, f1bf, Mrows, FFD, DDIM, 1, 0);
    gemm_bf16<<<dim3(DDIM / 128, Mrows / 64), 256, 0, stream>>>(
        f1bf, W2t, b2 + (size_t)lay * DDIM, ob, nullptr, Mrows, DDIM, FFD, 0, 0);
    add_ln_kernel<<<Mrows, 256, 0, stream>>>(h2, ob, g2 + (size_t)lay * DDIM, be2 + (size_t)lay * DDIM, h, hbf);
  }

  pool_kernel<<<(BB * DDIM + 255) / 256, 256, 0, stream>>>(h, pooled, BB * DDIM);
  head_kernel<<<BB, 256, 0, stream>>>(pooled, Wm1, bm1, Wm2, bm2, (float*)d_out);
}